// Round 15
// baseline (58.690 us; speedup 1.0000x reference)
//
#include <hip/hip_runtime.h>
#include <hip/hip_bf16.h>

// out[b,t,u,c] = enc[b,t,:]·W[c,:512] + dec[b,u,:]·W[c,512:]
// B=4, T=256, U=64, D=512, C=1024. Output 256 MiB fp32 (write floor ~39us).
//
// K1 cvt:   fp32 -> bf16 + MFMA-fragment permute (R12-proven).
// K2 dec:   bf16-MFMA dec projection -> Pd, fragment loads (R12-proven).
// K3 fused: 1024-thread blocks (16 waves), tile 16 bt x 256 c, grid (4,64).
//           Wave w: GEMM cb column w (16 k-steps), barrier, hoist enc row,
//           then stream bt-row w: per u one L2 Pd load + ONE 1 KiB CONTIGUOUS
//           cached wave-store (fill-shaped) at 16 waves/CU.
//           R12 lesson kept: plain cached stores, never nontemporal.

typedef float v4f   __attribute__((ext_vector_type(4)));
typedef float f32x4 __attribute__((ext_vector_type(4)));
typedef __attribute__((ext_vector_type(8))) short short8;

__device__ inline short bf16_of(float f) {
    __hip_bfloat16 h = __float2bfloat16(f);   // RNE
    return *reinterpret_cast<short*>(&h);
}

// ---------------- K1: fp32 -> bf16 fragment-layout permute (R12) -------------
//   [0,1024) enc | [1024,1280) dec | [1280,2304) Wenc | [2304,3328) Wdec
__global__ __launch_bounds__(256) void cvt_frag(
    const float* __restrict__ enc, const float* __restrict__ dec,
    const float* __restrict__ W,
    ushort* __restrict__ Xe_f, ushort* __restrict__ Xd_f,
    ushort* __restrict__ We_f, ushort* __restrict__ Wd_f)
{
    const int tid  = threadIdx.x;
    const int lane = tid & 63;
    const int l16  = lane & 15;
    const int kq   = lane >> 4;
    const int gid  = blockIdx.x * 4 + (tid >> 6);

    const float* src; ushort* dst; int g, rs, co;
    if (gid < 1024)      { src = enc; dst = Xe_f; g = gid;        rs = 512;  co = 0;   }
    else if (gid < 1280) { src = dec; dst = Xd_f; g = gid - 1024; rs = 512;  co = 0;   }
    else if (gid < 2304) { src = W;   dst = We_f; g = gid - 1280; rs = 1024; co = 0;   }
    else                 { src = W;   dst = Wd_f; g = gid - 2304; rs = 1024; co = 512; }

    const int rb = g >> 4, kbi = g & 15;
    const float* p = src + (size_t)(rb * 16 + l16) * rs + co + kbi * 32 + kq * 8;
    float4 lo = *(const float4*)p;
    float4 hi = *(const float4*)(p + 4);
    short8 o;
    o[0] = bf16_of(lo.x); o[1] = bf16_of(lo.y); o[2] = bf16_of(lo.z); o[3] = bf16_of(lo.w);
    o[4] = bf16_of(hi.x); o[5] = bf16_of(hi.y); o[6] = bf16_of(hi.z); o[7] = bf16_of(hi.w);
    *(short8*)&dst[(size_t)g * 512 + lane * 8] = o;
}

// ---------------- K2: dec projection GEMM (R12) ------------------------------
__global__ __launch_bounds__(256) void dec_gemm_bf16(
    const ushort* __restrict__ Xd_f, const ushort* __restrict__ Wd_f,
    float* __restrict__ Pd)
{
    const int tid  = threadIdx.x;
    const int wave = tid >> 6;
    const int lane = tid & 63;
    const int l16  = lane & 15;
    const int kq   = lane >> 4;

    const int kz = wave >> 1;
    const int wn = (wave & 1) * 32;
    const int mb = blockIdx.y;
    const int cBase = blockIdx.x * 64;
    const int cb0 = blockIdx.x * 4 + (wave & 1) * 2;

    const short8* xa  = (const short8*)Xd_f + (size_t)(mb  * 16 + kz * 8) * 64 + lane;
    const short8* wb0 = (const short8*)Wd_f + (size_t)(cb0       * 16 + kz * 8) * 64 + lane;
    const short8* wb1 = (const short8*)Wd_f + (size_t)((cb0 + 1) * 16 + kz * 8) * 64 + lane;

    f32x4 a0 = {0.f,0.f,0.f,0.f}, a1 = {0.f,0.f,0.f,0.f};
#pragma unroll
    for (int s = 0; s < 8; ++s) {
        short8 a  = xa [(size_t)s * 64];
        short8 b0 = wb0[(size_t)s * 64];
        short8 b1 = wb1[(size_t)s * 64];
        a0 = __builtin_amdgcn_mfma_f32_16x16x32_bf16(a, b0, a0, 0, 0, 0);
        a1 = __builtin_amdgcn_mfma_f32_16x16x32_bf16(a, b1, a1, 0, 0, 0);
    }

    __shared__ float Ps[16][65];
    if (kz == 1) {
#pragma unroll
        for (int r = 0; r < 4; ++r) {
            Ps[kq * 4 + r][wn + l16]      = a0[r];
            Ps[kq * 4 + r][wn + 16 + l16] = a1[r];
        }
    }
    __syncthreads();
    if (kz == 0) {
        float* p0 = Pd + (size_t)(mb * 16) * 1024 + cBase + wn;
#pragma unroll
        for (int r = 0; r < 4; ++r) {
            const int row = kq * 4 + r;
            p0[(size_t)row * 1024 + l16]      = a0[r] + Ps[row][wn + l16];
            p0[(size_t)row * 1024 + 16 + l16] = a1[r] + Ps[row][wn + 16 + l16];
        }
    }
}

// ---------------- K3: fused enc GEMM + 1 KiB-store stream --------------------
// Grid (4 c-tiles, 64 bt-tiles), 1024 threads = 16 waves.
__global__ __launch_bounds__(1024) void fused_enc_stream(
    const ushort* __restrict__ Xe_f,  // frag layout (64 mb x 16 kb)
    const ushort* __restrict__ We_f,  // frag layout (64 cb x 16 kb)
    const float* __restrict__ Pd,     // (256, 1024)
    float* __restrict__ out)          // (1024, 64, 1024)
{
    const int tid  = threadIdx.x;
    const int w    = tid >> 6;        // wave 0..15 = bt row AND cb column
    const int lane = tid & 63;
    const int l16  = lane & 15;
    const int kq   = lane >> 4;

    const int btBase = blockIdx.y * 16;
    const int cBase  = blockIdx.x * 256;
    const int b      = blockIdx.y >> 4;
    const int cb     = blockIdx.x * 16 + w;

    __shared__ float encS[16][260];   // 16 bt rows x 256 c (+pad), 16.6 KiB

    // (1) Enc GEMM: wave w computes the 16bt x 16c sub-tile for cb, full K.
    {
        const short8* xa = (const short8*)Xe_f + (size_t)(blockIdx.y * 16) * 64 + lane;
        const short8* wb = (const short8*)We_f + (size_t)(cb * 16) * 64 + lane;
        f32x4 acc = {0.f, 0.f, 0.f, 0.f};
#pragma unroll
        for (int s = 0; s < 16; ++s) {
            short8 a  = xa[(size_t)s * 64];
            short8 bf = wb[(size_t)s * 64];
            acc = __builtin_amdgcn_mfma_f32_16x16x32_bf16(a, bf, acc, 0, 0, 0);
        }
#pragma unroll
        for (int r = 0; r < 4; ++r)            // D: col=l16, row=kq*4+r
            encS[kq * 4 + r][w * 16 + l16] = acc[r];
    }

    __syncthreads();

    // (2) Wave w streams bt-row btBase+w: hoist enc row slice to regs.
    const float4 e = *(const float4*)&encS[w][lane * 4];

    const float* pd = Pd + (size_t)(b * 64) * 1024 + cBase + lane * 4;
    float*       po = out + ((size_t)(btBase + w) * 64) * 1024 + cBase + lane * 4;

    // Per u: one L2-broadcast Pd float4 + add + ONE 1 KiB contiguous
    // cached wave-store.
#pragma unroll 8
    for (int u = 0; u < 64; ++u) {
        float4 d = *(const float4*)&pd[(size_t)u * 1024];
        v4f r = {e.x + d.x, e.y + d.y, e.z + d.z, e.w + d.w};
        *(v4f*)&po[(size_t)u * 1024] = r;
    }
}

extern "C" void kernel_launch(void* const* d_in, const int* in_sizes, int n_in,
                              void* d_out, int out_size, void* d_ws, size_t ws_size,
                              hipStream_t stream) {
    const float* enc = (const float*)d_in[0];   // (4,256,512)
    const float* dec = (const float*)d_in[1];   // (4,64,512)
    const float* W   = (const float*)d_in[2];   // (1024,1024)
    float* out = (float*)d_out;

    // Workspace: Pd 1 MiB | Xe_f 1 MiB | Xd_f 256 KiB | We_f 1 MiB | Wd_f 1 MiB
    char* ws = (char*)d_ws;
    float*  Pd   = (float*)(ws);
    ushort* Xe_f = (ushort*)(ws + (1u << 20));
    ushort* Xd_f = (ushort*)(ws + (2u << 20));
    ushort* We_f = (ushort*)(ws + (2u << 20) + (1u << 18));
    ushort* Wd_f = (ushort*)(ws + (3u << 20) + (1u << 18));

    cvt_frag<<<dim3(832), 256, 0, stream>>>(enc, dec, W, Xe_f, Xd_f, We_f, Wd_f);
    dec_gemm_bf16<<<dim3(16, 16), 256, 0, stream>>>(Xd_f, Wd_f, Pd);
    fused_enc_stream<<<dim3(4, 64), 1024, 0, stream>>>(Xe_f, We_f, Pd, out);
}

// Round 16
// 56.215 us; speedup vs baseline: 1.0440x; 1.0440x over previous
//
#include <hip/hip_runtime.h>
#include <hip/hip_bf16.h>

// out[b,t,u,c] = enc[b,t,:]·W[c,:512] + dec[b,u,:]·W[c,512:]
// B=4, T=256, U=64, D=512, C=1024. Output 256 MiB fp32 (write floor ~39us).
//
// FINAL (R12 config — best measured 56.0us):
// K1 cvt:   fp32 -> bf16 + permute into MFMA-fragment order (1 KB wave-loads).
// K2 dec:   bf16-MFMA dec projection -> Pd (256x1024), fragment loads,
//           2-way split-K through LDS.
// K3 fused: per block (16 bt x 64 c): Pd chunk -> decS (LDS), enc MFMA tile
//           (frag loads, split-K) -> encS, barrier, stream 256 KiB with
//           plain cached float4 stores.
// Key lessons encoded: (a) nontemporal stores throttle streaming writes ~22%
// on gfx950 — use cached stores; (b) MFMA operands must be pre-permuted to
// fragment order for coalesced loads; (c) occupancy >> store width for the
// write stream; (d) grid.sync costs ~400us at 1024 blocks — never use.

typedef float v4f   __attribute__((ext_vector_type(4)));
typedef float f32x4 __attribute__((ext_vector_type(4)));
typedef __attribute__((ext_vector_type(8))) short short8;

__device__ inline short bf16_of(float f) {
    __hip_bfloat16 h = __float2bfloat16(f);   // RNE
    return *reinterpret_cast<short*>(&h);
}

// ---------------- K1: fp32 -> bf16 fragment-layout permute -------------------
// One wave per 16x32 fragment block (1 KiB out). Wave-task ids:
//   [0,1024) enc | [1024,1280) dec | [1280,2304) Wenc | [2304,3328) Wdec
__global__ __launch_bounds__(256) void cvt_frag(
    const float* __restrict__ enc, const float* __restrict__ dec,
    const float* __restrict__ W,
    ushort* __restrict__ Xe_f, ushort* __restrict__ Xd_f,
    ushort* __restrict__ We_f, ushort* __restrict__ Wd_f)
{
    const int tid  = threadIdx.x;
    const int lane = tid & 63;
    const int l16  = lane & 15;
    const int kq   = lane >> 4;
    const int gid  = blockIdx.x * 4 + (tid >> 6);

    const float* src; ushort* dst; int g, rs, co;
    if (gid < 1024)      { src = enc; dst = Xe_f; g = gid;        rs = 512;  co = 0;   }
    else if (gid < 1280) { src = dec; dst = Xd_f; g = gid - 1024; rs = 512;  co = 0;   }
    else if (gid < 2304) { src = W;   dst = We_f; g = gid - 1280; rs = 1024; co = 0;   }
    else                 { src = W;   dst = Wd_f; g = gid - 2304; rs = 1024; co = 512; }

    const int rb = g >> 4, kbi = g & 15;
    const float* p = src + (size_t)(rb * 16 + l16) * rs + co + kbi * 32 + kq * 8;
    float4 lo = *(const float4*)p;
    float4 hi = *(const float4*)(p + 4);
    short8 o;
    o[0] = bf16_of(lo.x); o[1] = bf16_of(lo.y); o[2] = bf16_of(lo.z); o[3] = bf16_of(lo.w);
    o[4] = bf16_of(hi.x); o[5] = bf16_of(hi.y); o[6] = bf16_of(hi.z); o[7] = bf16_of(hi.w);
    *(short8*)&dst[(size_t)g * 512 + lane * 8] = o;
}

// ---------------- K2: dec projection GEMM (fragment loads, split-K) ----------
__global__ __launch_bounds__(256) void dec_gemm_bf16(
    const ushort* __restrict__ Xd_f, const ushort* __restrict__ Wd_f,
    float* __restrict__ Pd)
{
    const int tid  = threadIdx.x;
    const int wave = tid >> 6;
    const int lane = tid & 63;
    const int l16  = lane & 15;
    const int kq   = lane >> 4;

    const int kz = wave >> 1;
    const int wn = (wave & 1) * 32;
    const int mb = blockIdx.y;
    const int cBase = blockIdx.x * 64;
    const int cb0 = blockIdx.x * 4 + (wave & 1) * 2;

    const short8* xa  = (const short8*)Xd_f + (size_t)(mb  * 16 + kz * 8) * 64 + lane;
    const short8* wb0 = (const short8*)Wd_f + (size_t)(cb0       * 16 + kz * 8) * 64 + lane;
    const short8* wb1 = (const short8*)Wd_f + (size_t)((cb0 + 1) * 16 + kz * 8) * 64 + lane;

    f32x4 a0 = {0.f,0.f,0.f,0.f}, a1 = {0.f,0.f,0.f,0.f};
#pragma unroll
    for (int s = 0; s < 8; ++s) {
        short8 a  = xa [(size_t)s * 64];
        short8 b0 = wb0[(size_t)s * 64];
        short8 b1 = wb1[(size_t)s * 64];
        a0 = __builtin_amdgcn_mfma_f32_16x16x32_bf16(a, b0, a0, 0, 0, 0);
        a1 = __builtin_amdgcn_mfma_f32_16x16x32_bf16(a, b1, a1, 0, 0, 0);
    }

    __shared__ float Ps[16][65];
    if (kz == 1) {
#pragma unroll
        for (int r = 0; r < 4; ++r) {
            Ps[kq * 4 + r][wn + l16]      = a0[r];
            Ps[kq * 4 + r][wn + 16 + l16] = a1[r];
        }
    }
    __syncthreads();
    if (kz == 0) {
        float* p0 = Pd + (size_t)(mb * 16) * 1024 + cBase + wn;
#pragma unroll
        for (int r = 0; r < 4; ++r) {
            const int row = kq * 4 + r;
            p0[(size_t)row * 1024 + l16]      = a0[r] + Ps[row][wn + l16];
            p0[(size_t)row * 1024 + 16 + l16] = a1[r] + Ps[row][wn + 16 + l16];
        }
    }
}

// ---------------- K3: fused enc GEMM + broadcast-add stream ------------------
// Grid (16 c-tiles, 64 bt-tiles), 256 threads = 4 waves.
__global__ __launch_bounds__(256) void fused_enc_stream(
    const ushort* __restrict__ Xe_f,  // frag layout (64 mb x 16 kb)
    const ushort* __restrict__ We_f,  // frag layout (64 cb x 16 kb)
    const float* __restrict__ Pd,     // (256, 1024)
    float* __restrict__ out)          // (1024, 64, 1024)
{
    const int tid  = threadIdx.x;
    const int wave = tid >> 6;
    const int lane = tid & 63;
    const int l16  = lane & 15;
    const int kq   = lane >> 4;

    const int kz = wave >> 1;
    const int wn = (wave & 1) * 32;
    const int btBase = blockIdx.y * 16;
    const int cBase  = blockIdx.x * 64;
    const int b      = blockIdx.y >> 4;
    const int cb0    = blockIdx.x * 4 + (wave & 1) * 2;

    __shared__ float encS[2][16][68];
    __shared__ float decS[64][64];

    // Stage decS: 4096 floats = 4 float4 per thread.
#pragma unroll
    for (int p = 0; p < 4; ++p) {
        int s    = tid + p * 256;
        int row  = s >> 4;
        int slot = s & 15;
        float4 v = *(const float4*)&Pd[(size_t)(b * 64 + row) * 1024 + cBase + slot * 4];
        *(float4*)&decS[row][slot * 4] = v;
    }

    // Enc GEMM: 16 x 64 tile, fragment loads, 2-way split-K.
    {
        const short8* xa  = (const short8*)Xe_f + (size_t)(blockIdx.y * 16 + kz * 8) * 64 + lane;
        const short8* wb0 = (const short8*)We_f + (size_t)(cb0       * 16 + kz * 8) * 64 + lane;
        const short8* wb1 = (const short8*)We_f + (size_t)((cb0 + 1) * 16 + kz * 8) * 64 + lane;
        f32x4 a0 = {0.f,0.f,0.f,0.f}, a1 = {0.f,0.f,0.f,0.f};
#pragma unroll
        for (int s = 0; s < 8; ++s) {
            short8 a  = xa [(size_t)s * 64];
            short8 b0 = wb0[(size_t)s * 64];
            short8 b1 = wb1[(size_t)s * 64];
            a0 = __builtin_amdgcn_mfma_f32_16x16x32_bf16(a, b0, a0, 0, 0, 0);
            a1 = __builtin_amdgcn_mfma_f32_16x16x32_bf16(a, b1, a1, 0, 0, 0);
        }
#pragma unroll
        for (int r = 0; r < 4; ++r) {        // D: col=l16, row=kq*4+r
            encS[kz][kq * 4 + r][wn + l16]      = a0[r];
            encS[kz][kq * 4 + r][wn + 16 + l16] = a1[r];
        }
    }

    __syncthreads();

    // Stream: thread (row=tid>>4, slot=tid&15); decS from LDS, cached stores.
    const int row = tid >> 4;
    const int c4  = (tid & 15) * 4;

    const float4 e0 = *(const float4*)&encS[0][row][c4];
    const float4 e1 = *(const float4*)&encS[1][row][c4];
    const v4f e = {e0.x + e1.x, e0.y + e1.y, e0.z + e1.z, e0.w + e1.w};

    float* po = out + (size_t)(btBase + row) * 64 * 1024 + cBase + c4;

#pragma unroll 8
    for (int u = 0; u < 64; ++u) {
        float4 d = *(const float4*)&decS[u][c4];
        v4f r = {e.x + d.x, e.y + d.y, e.z + d.z, e.w + d.w};
        *(v4f*)&po[(size_t)u * 1024] = r;
    }
}

extern "C" void kernel_launch(void* const* d_in, const int* in_sizes, int n_in,
                              void* d_out, int out_size, void* d_ws, size_t ws_size,
                              hipStream_t stream) {
    const float* enc = (const float*)d_in[0];   // (4,256,512)
    const float* dec = (const float*)d_in[1];   // (4,64,512)
    const float* W   = (const float*)d_in[2];   // (1024,1024)
    float* out = (float*)d_out;

    // Workspace: Pd 1 MiB | Xe_f 1 MiB | Xd_f 256 KiB | We_f 1 MiB | Wd_f 1 MiB
    char* ws = (char*)d_ws;
    float*  Pd   = (float*)(ws);
    ushort* Xe_f = (ushort*)(ws + (1u << 20));
    ushort* Xd_f = (ushort*)(ws + (2u << 20));
    ushort* We_f = (ushort*)(ws + (2u << 20) + (1u << 18));
    ushort* Wd_f = (ushort*)(ws + (3u << 20) + (1u << 18));

    cvt_frag<<<dim3(832), 256, 0, stream>>>(enc, dec, W, Xe_f, Xd_f, We_f, Wd_f);
    dec_gemm_bf16<<<dim3(16, 16), 256, 0, stream>>>(Xd_f, Wd_f, Pd);
    fused_enc_stream<<<dim3(16, 64), 256, 0, stream>>>(Xe_f, We_f, Pd, out);
}